// Round 1
// 360.163 us; speedup vs baseline: 1.0162x; 1.0162x over previous
//
#include <hip/hip_runtime.h>
#include <hip/hip_bf16.h>

// HMM forward-backward, B=128, T=1024, K=256.
// P = (diag-offd)*I + offd*J  -> (v@P)[j] = offd*sum(v) + (diag-offd)*v[j].
//
// R3: latency-slimmed recursion.
//  * Deferred-S dataflow: S_t = cd*R_t + C1[t]*S_{t-1}, R_t = sum_j(y_t*v_{t-1}),
//    C1[t] = offd*sum_j(y_t) precomputed in the sigmoid pass. The 9-level
//    wave reduce now hangs off v (ready 2 ops after S_{t-2}), so the serial
//    S->S chain is ~7 ops/step instead of ~12.
//  * Loop-carried 16-deep register ring (consume slot, refill same slot) so
//    the compiler cannot sink the prefetch loads (old kernel: VGPR_Count=64
//    proved the 24-deep ring was collapsed). Unguarded prefetch; y sits in
//    d_out scratch with 8KB pad before and C1 after, so over/under-reads land
//    in allocated memory.
//  * v_cvt_pk_bf16_f32 packing (1 inst per 2 values) instead of bit-twiddle.
//  * y + C1 live in d_out (dead until hmm_post overwrites); ws = alpha|beta.

constexpr int BB = 128;
constexpr int TT = 1024;
constexpr int KK = 256;
constexpr int PF = 16;           // prefetch depth (rows == steps)
constexpr size_t YPAD = 8192;    // underread pad for backward prefetch

// ---------- DPP wave-64 sum reduction -> broadcast scalar ----------
template <int CTRL, int RM>
__device__ __forceinline__ float dpp_add(float v) {
  int t = __builtin_amdgcn_update_dpp(0, __float_as_int(v), CTRL, RM, 0xf, true);
  return v + __int_as_float(t);
}

__device__ __forceinline__ float wred_dpp(float v) {
  v = dpp_add<0x111, 0xf>(v);  // row_shr:1
  v = dpp_add<0x112, 0xf>(v);  // row_shr:2
  v = dpp_add<0x114, 0xf>(v);  // row_shr:4
  v = dpp_add<0x118, 0xf>(v);  // row_shr:8  -> lane 15 of each row = row sum
  v = dpp_add<0x142, 0xa>(v);  // row_bcast:15
  v = dpp_add<0x143, 0xc>(v);  // row_bcast:31 -> lane63 = total
  return __int_as_float(__builtin_amdgcn_readlane(__float_as_int(v), 63));
}

__device__ __forceinline__ float fsig(float x) {
  return __builtin_amdgcn_rcpf(1.0f + __expf(-x));
}

__device__ __forceinline__ unsigned cvtpk_bf16(float lo, float hi) {
  unsigned r;
  asm("v_cvt_pk_bf16_f32 %0, %1, %2" : "=v"(r) : "v"(lo), "v"(hi));
  return r;  // [15:0]=bf16(lo) [31:16]=bf16(hi), RNE
}
__device__ __forceinline__ float lo16f(unsigned u) { return __uint_as_float(u << 16); }
__device__ __forceinline__ float hi16f(unsigned u) { return __uint_as_float(u & 0xffff0000u); }
__device__ __forceinline__ float bf2f(unsigned short u) {
  return __uint_as_float((unsigned)u << 16);
}

// ---------- pass 0: y = sigmoid(x) bf16 rows + C1[row] = offd*sum(y_row) ----
__global__ __launch_bounds__(256) void sig_pass2(const float* __restrict__ x,
                                                 uint2* __restrict__ y,
                                                 float* __restrict__ C1,
                                                 const float* __restrict__ P) {
  const int lane = threadIdx.x & 63;
  const size_t row = ((size_t)blockIdx.x << 2) | (threadIdx.x >> 6);  // b*TT+t
  const float4 v = reinterpret_cast<const float4*>(x)[row * 64 + lane];
  const unsigned p01 = cvtpk_bf16(fsig(v.x), fsig(v.y));
  const unsigned p23 = cvtpk_bf16(fsig(v.z), fsig(v.w));
  y[row * 64 + lane] = make_uint2(p01, p23);
  // sum the ROUNDED values so C1 matches what the recursion actually uses
  const float s = wred_dpp((lo16f(p01) + hi16f(p01)) + (lo16f(p23) + hi16f(p23)));
  if (lane == 0) C1[row] = P[1] * s;
}

// ---------- pass 1: forward/backward recursions ----------
__global__ __launch_bounds__(64, 1) void hmm_recur2(
    const uint2* __restrict__ y, const float* __restrict__ C1,
    const float* __restrict__ P, const float* __restrict__ p0,
    uint2* __restrict__ alpha, uint2* __restrict__ beta) {
  const int seq = blockIdx.x;   // 0..255
  const int lane = threadIdx.x; // 0..63
  const float diag = P[0];
  const float offd = P[1];
  const float cd = diag - offd;
  const float cod = offd;

  uint2 ring[PF];

  if (seq < BB) {
    // ---------------- forward: alpha (unnormalized, periodic rescale) -------
    const int b = seq;
    const uint2* yb = y + (size_t)b * TT * 64;
    uint2* ar = alpha + (size_t)b * TT * 64;
    const float* c1b = C1 + (size_t)b * TT;

    const uint2 yv0 = yb[lane];
#pragma unroll
    for (int i = 0; i < PF; ++i) ring[i] = yb[(size_t)(1 + i) * 64 + lane];

    const float4 pv = reinterpret_cast<const float4*>(p0)[lane];
    float v0 = pv.x * lo16f(yv0.x), v1 = pv.y * hi16f(yv0.x);
    float v2 = pv.z * lo16f(yv0.y), v3 = pv.w * hi16f(yv0.y);
    float S = wred_dpp((v0 + v1) + (v2 + v3));
    ar[lane] = make_uint2(cvtpk_bf16(v0, v1), cvtpk_bf16(v2, v3));

#define FSTEP(T_, SLOT_)                                                   \
  {                                                                        \
    const uint2 yv = ring[SLOT_];                                          \
    ring[SLOT_] = yb[(size_t)((T_) + PF) * 64 + lane];                     \
    const float y0 = lo16f(yv.x), y1 = hi16f(yv.x);                        \
    const float y2 = lo16f(yv.y), y3 = hi16f(yv.y);                        \
    const float R = wred_dpp((y0 * v0 + y1 * v1) + (y2 * v2 + y3 * v3));   \
    const float Sn = cd * R + c1v * S;                                     \
    const float sc = cod * S;                                              \
    v0 = y0 * (cd * v0 + sc); v1 = y1 * (cd * v1 + sc);                    \
    v2 = y2 * (cd * v2 + sc); v3 = y3 * (cd * v3 + sc);                    \
    ar[(size_t)(T_) * 64 + lane] =                                         \
        make_uint2(cvtpk_bf16(v0, v1), cvtpk_bf16(v2, v3));                \
    S = Sn;                                                                \
  }

    // peeled group: steps t=1..15 (slot = t-1)
#pragma unroll
    for (int i = 0; i < 15; ++i) {
      const float c1v = c1b[i + 1];
      FSTEP(i + 1, i);
    }
    {
      const float rr = __builtin_amdgcn_rcpf(S);
      v0 *= rr; v1 *= rr; v2 *= rr; v3 *= rr; S = 1.0f;
    }

#pragma unroll 1
    for (int g = 1; g < 64; ++g) {   // steps t = 16g .. 16g+15
      const int tb = g * 16;
      float c1g[16];
#pragma unroll
      for (int j = 0; j < 16; ++j) c1g[j] = c1b[tb + j];
#pragma unroll
      for (int i = 0; i < 16; ++i) {
        const int slot = (i + 15) & 15;
        const float c1v = c1g[i];
        FSTEP(tb + i, slot);
      }
      const float rr = __builtin_amdgcn_rcpf(S);
      v0 *= rr; v1 *= rr; v2 *= rr; v3 *= rr; S = 1.0f;
    }
#undef FSTEP
  } else {
    // ---------------- backward: beta (state m = y_{t+1} o beta_{t+1}) ------
    const int b = seq - BB;
    const uint2* yb = y + (size_t)b * TT * 64;
    uint2* br = beta + (size_t)b * TT * 64;
    const float* c1b = C1 + (size_t)b * TT;

    const uint2 yvL = yb[(size_t)(TT - 1) * 64 + lane];
#pragma unroll
    for (int i = 0; i < PF; ++i) ring[i] = yb[(size_t)(TT - 2 - i) * 64 + lane];

    float m0 = lo16f(yvL.x), m1 = hi16f(yvL.x);
    float m2 = lo16f(yvL.y), m3 = hi16f(yvL.y);
    float S = wred_dpp((m0 + m1) + (m2 + m3));
    br[(size_t)(TT - 1) * 64 + lane] = make_uint2(0x3F803F80u, 0x3F803F80u);

#define BSTEP(T_, SLOT_)                                                   \
  {                                                                        \
    const uint2 yv = ring[SLOT_];                                          \
    ring[SLOT_] = yb[(ptrdiff_t)((T_)-PF) * 64 + lane];                    \
    const float y0 = lo16f(yv.x), y1 = hi16f(yv.x);                        \
    const float y2 = lo16f(yv.y), y3 = hi16f(yv.y);                        \
    const float R = wred_dpp((y0 * m0 + y1 * m1) + (y2 * m2 + y3 * m3));   \
    const float Sn = cd * R + c1v * S;                                     \
    const float sc = cod * S;                                              \
    const float h0 = cd * m0 + sc, h1 = cd * m1 + sc;                      \
    const float h2 = cd * m2 + sc, h3 = cd * m3 + sc;                      \
    br[(size_t)(T_) * 64 + lane] =                                         \
        make_uint2(cvtpk_bf16(h0, h1), cvtpk_bf16(h2, h3));                \
    m0 = y0 * h0; m1 = y1 * h1; m2 = y2 * h2; m3 = y3 * h3;                \
    S = Sn;                                                                \
  }

    // peeled: steps k=0..14 -> t = 1022..1008 (slot = k)
#pragma unroll
    for (int k = 0; k < 15; ++k) {
      const float c1v = c1b[1022 - k];
      BSTEP(1022 - k, k);
    }
    {
      const float rr = __builtin_amdgcn_rcpf(S);
      m0 *= rr; m1 *= rr; m2 *= rr; m3 *= rr; S = 1.0f;
    }

#pragma unroll 1
    for (int g = 1; g < 64; ++g) {   // t = tb .. tb-15, tb = 1007-16(g-1)
      const int tb = 1007 - 16 * (g - 1);
      float c1g[16];
#pragma unroll
      for (int j = 0; j < 16; ++j) c1g[j] = c1b[tb - 15 + j];
#pragma unroll
      for (int i = 0; i < 16; ++i) {
        const int slot = (i + 15) & 15;
        const float c1v = c1g[15 - i];
        BSTEP(tb - i, slot);
      }
      const float rr = __builtin_amdgcn_rcpf(S);
      m0 *= rr; m1 *= rr; m2 *= rr; m3 *= rr; S = 1.0f;
    }
#undef BSTEP
  }
}

// ---------- pass 2: posterior = normalize(alpha*beta) ----------
__global__ __launch_bounds__(256) void hmm_post(
    const __hip_bfloat16* __restrict__ alpha,
    const __hip_bfloat16* __restrict__ beta, float* __restrict__ out) {
  const size_t gid = (size_t)blockIdx.x * 256 + threadIdx.x;
  const size_t row = gid >> 6;  // one wave per (b,t) row
  const int lane = (int)(gid & 63);
  const ushort4 av = reinterpret_cast<const ushort4*>(alpha)[row * 64 + lane];
  const ushort4 bv = reinterpret_cast<const ushort4*>(beta)[row * 64 + lane];
  const float g0 = bf2f(av.x) * bf2f(bv.x);
  const float g1 = bf2f(av.y) * bf2f(bv.y);
  const float g2 = bf2f(av.z) * bf2f(bv.z);
  const float g3 = bf2f(av.w) * bf2f(bv.w);
  const float s = wred_dpp((g0 + g1) + (g2 + g3));
  const float r = __builtin_amdgcn_rcpf(s);
  float4 o;
  o.x = g0 * r; o.y = g1 * r; o.z = g2 * r; o.w = g3 * r;
  reinterpret_cast<float4*>(out)[row * 64 + lane] = o;
}

extern "C" void kernel_launch(void* const* d_in, const int* in_sizes, int n_in,
                              void* d_out, int out_size, void* d_ws, size_t ws_size,
                              hipStream_t stream) {
  (void)in_sizes; (void)n_in; (void)out_size; (void)ws_size;
  const float* x = (const float*)d_in[0];
  const float* P = (const float*)d_in[1];
  const float* p0 = (const float*)d_in[2];
  float* out = (float*)d_out;
  const size_t elems = (size_t)BB * TT * KK;

  // ws: alpha | beta (bf16, 64MB each).
  uint2* alpha = (uint2*)d_ws;
  uint2* beta = alpha + elems / 4;
  // d_out doubles as scratch until hmm_post overwrites it:
  // [pad 8KB][y bf16 64MB][C1 512KB]  (fwd prefetch overreads into C1,
  // bwd prefetch underreads into pad -- both allocated, never consumed).
  uint2* y = (uint2*)((char*)d_out + YPAD);
  float* C1 = (float*)((char*)d_out + YPAD + elems * 2);

  sig_pass2<<<(int)(BB * TT / 4), 256, 0, stream>>>(x, y, C1, P);
  hmm_recur2<<<2 * BB, 64, 0, stream>>>(y, C1, P, p0, alpha, beta);
  hmm_post<<<(BB * TT) / 4, 256, 0, stream>>>(
      (const __hip_bfloat16*)alpha, (const __hip_bfloat16*)beta, out);
}